// Round 7
// baseline (169.985 us; speedup 1.0000x reference)
//
#include <hip/hip_runtime.h>
#include <hip/hip_bf16.h>
#include <stdint.h>

typedef unsigned short u16;
typedef signed char i8;

#define D_INNER 2048
#define D_OUTER 2048
#define MROWS   8192                 // B*S = 2*4096
#define W_ELEMS (D_OUTER * D_INNER)  // 4194304
#define NPART   1024                 // absmean partial blocks (each covers 1024 float4)

#define BM 128
#define BN 128
#define BK 128                       // i8 elements per K-tile (= 128 bytes/row, 8 16B groups)

// s_waitcnt imm: vmcnt[3:0]|vmcnt[5:4]<<14, expcnt[6:4]=7 (nowait), lgkmcnt[11:8]=15 (nowait)
#define WAIT_VMCNT_8 0x0F78

typedef __attribute__((ext_vector_type(4))) float f32x4;
typedef __attribute__((ext_vector_type(4))) int   i32x4;

// ------- 1) fused prep: blocks [0,8192) = RMSNorm rows -> i8 + per-row step;
//            blocks [8192,8192+1024) = |w| partials
__global__ __launch_bounds__(256) void prep_kernel(const float* __restrict__ x,
                            const float* __restrict__ g,
                            const float* __restrict__ w,
                            i8* __restrict__ xn, float* __restrict__ srow,
                            float* __restrict__ partials) {
  __shared__ float red[4];
  __shared__ float redm[4];
  int t = threadIdx.x;
  int lane = t & 63, wvi = t >> 6;

  if (blockIdx.x >= MROWS) {
    // ---- absmean partial: 4 float4/thread, 1024 blocks * 1024 float4 = full W ----
    int p = blockIdx.x - MROWS;                    // 0..1023
    int base = p * 1024;
    float s = 0.f;
#pragma unroll
    for (int r = 0; r < 4; ++r) {
      f32x4 v = ((const f32x4*)w)[base + r * 256 + t];
      s += fabsf(v[0]) + fabsf(v[1]) + fabsf(v[2]) + fabsf(v[3]);
    }
    for (int off = 32; off; off >>= 1) s += __shfl_down(s, off, 64);
    if (lane == 0) red[wvi] = s;
    __syncthreads();
    if (t == 0) partials[p] = red[0] + red[1] + red[2] + red[3];
    return;
  }

  // ---- RMSNorm one row -> per-row i8 quantization ----
  int row = blockIdx.x;
  const f32x4* xr = (const f32x4*)(x + (size_t)row * D_INNER);   // 512 float4/row
  i8* xo = xn + (size_t)row * D_INNER;

  f32x4 v0 = __builtin_nontemporal_load(&xr[t]);
  f32x4 v1 = __builtin_nontemporal_load(&xr[t + 256]);
  const f32x4* gr = (const f32x4*)g;
  f32x4 g0 = gr[t], g1 = gr[t + 256];

  float s = v0[0]*v0[0] + v0[1]*v0[1] + v0[2]*v0[2] + v0[3]*v0[3]
          + v1[0]*v1[0] + v1[1]*v1[1] + v1[2]*v1[2] + v1[3]*v1[3];
  float m = fmaxf(fmaxf(fmaxf(fabsf(v0[0]*g0[0]), fabsf(v0[1]*g0[1])),
                        fmaxf(fabsf(v0[2]*g0[2]), fabsf(v0[3]*g0[3]))),
                  fmaxf(fmaxf(fabsf(v1[0]*g1[0]), fabsf(v1[1]*g1[1])),
                        fmaxf(fabsf(v1[2]*g1[2]), fabsf(v1[3]*g1[3]))));
  for (int off = 32; off; off >>= 1) {
    s += __shfl_down(s, off, 64);
    m = fmaxf(m, __shfl_down(m, off, 64));
  }
  if (lane == 0) { red[wvi] = s; redm[wvi] = m; }
  __syncthreads();
  float total = red[0] + red[1] + red[2] + red[3];
  float rmax  = fmaxf(fmaxf(redm[0], redm[1]), fmaxf(redm[2], redm[3]));
  float invr = 1.0f / sqrtf(total * (1.0f / (float)D_INNER) + 1e-6f);

  float amax = fmaxf(rmax * invr, 1e-12f);   // max |xn| this row
  float step = amax * (1.0f / 127.0f);       // dequant step
  float qs   = 127.0f / amax;                // quant scale
  if (t == 0) srow[row] = step;

  char4 q0, q1;
  float qv;
  qv = fminf(127.f, fmaxf(-127.f, rintf(v0[0]*invr*g0[0]*qs))); q0.x = (i8)(int)qv;
  qv = fminf(127.f, fmaxf(-127.f, rintf(v0[1]*invr*g0[1]*qs))); q0.y = (i8)(int)qv;
  qv = fminf(127.f, fmaxf(-127.f, rintf(v0[2]*invr*g0[2]*qs))); q0.z = (i8)(int)qv;
  qv = fminf(127.f, fmaxf(-127.f, rintf(v0[3]*invr*g0[3]*qs))); q0.w = (i8)(int)qv;
  qv = fminf(127.f, fmaxf(-127.f, rintf(v1[0]*invr*g1[0]*qs))); q1.x = (i8)(int)qv;
  qv = fminf(127.f, fmaxf(-127.f, rintf(v1[1]*invr*g1[1]*qs))); q1.y = (i8)(int)qv;
  qv = fminf(127.f, fmaxf(-127.f, rintf(v1[2]*invr*g1[2]*qs))); q1.z = (i8)(int)qv;
  qv = fminf(127.f, fmaxf(-127.f, rintf(v1[3]*invr*g1[3]*qs))); q1.w = (i8)(int)qv;
  ((char4*)xo)[t]       = q0;
  ((char4*)xo)[t + 256] = q1;
}

// ------- 2) ternary quantize -> i8; block0 publishes gamma -------
__global__ __launch_bounds__(256) void quant_kernel(const float* __restrict__ w,
                             const float* __restrict__ partials,
                             float* __restrict__ gamma_out, i8* __restrict__ wq) {
  // every block re-reduces the 1024 partials (one float4/thread; deterministic)
  f32x4 pv = ((const f32x4*)partials)[threadIdx.x];
  double d = (double)pv[0] + (double)pv[1] + (double)pv[2] + (double)pv[3];
  for (int off = 32; off; off >>= 1) d += __shfl_down(d, off, 64);
  __shared__ double red[4];
  int lane = threadIdx.x & 63, wvi = threadIdx.x >> 6;
  if (lane == 0) red[wvi] = d;
  __syncthreads();
  double total = red[0] + red[1] + red[2] + red[3];
  float gamma = (float)(total * (1.0 / (double)W_ELEMS));
  float inv = 1.0f / (gamma + 1e-8f);
  if (blockIdx.x == 0 && threadIdx.x == 0) *gamma_out = gamma;

  int tid = blockIdx.x * blockDim.x + threadIdx.x;
  int stride = gridDim.x * blockDim.x;               // 2048*256 -> 2 iterations
  for (int i = tid; i < W_ELEMS / 4; i += stride) {
    f32x4 v = ((const f32x4*)w)[i];
    char4 q;
    q.x = (i8)(int)fminf(1.f, fmaxf(-1.f, rintf(v[0] * inv)));
    q.y = (i8)(int)fminf(1.f, fmaxf(-1.f, rintf(v[1] * inv)));
    q.z = (i8)(int)fminf(1.f, fmaxf(-1.f, rintf(v[2] * inv)));
    q.w = (i8)(int)fminf(1.f, fmaxf(-1.f, rintf(v[3] * inv)));
    ((char4*)wq)[i] = q;
  }
}

// ------- 3) i8 GEMM, double-buffered pipeline -------
// C[M,N] = (qA[M,K] * Wq[N,K]^T) * gamma * step_row, i32 accumulation (exact).
// Raw s_barrier + manual s_waitcnt vmcnt(8): tile k+1's global_load_lds stay in
// flight across tile k's MFMAs (no vmcnt(0) drain). XOR-swizzled LDS
// (conflict-free b128), XCD-aware grid remap (B half L2-resident per XCD).
__global__ __launch_bounds__(256) void gemm_bt(const i8* __restrict__ A,
                                               const i8* __restrict__ Bw,
                                               const float* __restrict__ gamma_p,
                                               const float* __restrict__ srow,
                                               float* __restrict__ C) {
  __shared__ __align__(16) i8 As[2][BM * BK];   // 2 x 16 KB
  __shared__ __align__(16) i8 Bs[2][BN * BK];   // 2 x 16 KB

  int f   = blockIdx.y * 16 + blockIdx.x;   // x-fastest dispatch order, 0..1023
  int xcd = f & 7;
  int gg  = f >> 3;                         // 0..127
  int nb  = (xcd >> 2) * 8 + (gg & 7);      // 0..15  (XCD-group owns an N-half)
  int mb  = (gg >> 3) * 4 + (xcd & 3);      // 0..63  (A tile hot across 8 n-steps)
  int bm0 = mb * BM;
  int bn0 = nb * BN;

  int tid  = threadIdx.x;
  int lane = tid & 63;
  int wv   = tid >> 6;
  int wm   = (wv >> 1) * 64;   // wave row offset in tile
  int wn   = (wv & 1) * 64;    // wave col offset in tile
  int lm   = lane & 15;        // m (or n) within 16
  int kg   = lane >> 4;        // k-group 0..3
  int sw   = lm & 7;           // read-side XOR swizzle (row&7 == lm&7 here)

  i32x4 acc[4][4] = {};

  const i8* Ag = A  + (size_t)bm0 * D_INNER;
  const i8* Bg = Bw + (size_t)bn0 * D_INNER;

  // per-thread staging pattern: 4 chunks for A, 4 for B (16B each)
#define STAGE(GP, LP, KOFF)                                                     \
  _Pragma("unroll")                                                             \
  for (int r = 0; r < 4; ++r) {                                                 \
    int ci = r * 256 + tid;                                                     \
    int row = ci >> 3;                                                          \
    int kc = (((ci & 7) ^ (row & 7)) << 4);                                     \
    __builtin_amdgcn_global_load_lds(                                           \
        (const __attribute__((address_space(1))) void*)(GP + (size_t)row * D_INNER + (KOFF) + kc), \
        (__attribute__((address_space(3))) void*)((LP) + ci * 16), 16, 0, 0);   \
  }

  // prologue: tile 0 -> buffer 0
  STAGE(Ag, &As[0][0], 0)
  STAGE(Bg, &Bs[0][0], 0)

  for (int it = 0; it < D_INNER / BK; ++it) {   // 16 iterations
    int cur = it & 1, nxt = cur ^ 1;
    int koff = ((it + 1) & 15) * BK;            // last iter wraps to tile 0 (valid, discarded)

    __builtin_amdgcn_s_barrier();               // all waves done reading buf[nxt]
    STAGE(Ag, &As[nxt][0], koff)                // prefetch tile it+1 (no wait)
    STAGE(Bg, &Bs[nxt][0], koff)
    __builtin_amdgcn_s_waitcnt(WAIT_VMCNT_8);   // my 8 oldest (tile it) loads landed
    __builtin_amdgcn_s_barrier();               // everyone's tile-it loads landed

    const i8* Ab = &As[cur][0];
    const i8* Bb = &Bs[cur][0];
#pragma unroll
    for (int s = 0; s < 2; ++s) {               // two K=64 MFMA steps per tile
      int gsel = s * 4 + kg;                    // 16B group index before swizzle
      i32x4 af[4], bb[4];
#pragma unroll
      for (int i = 0; i < 4; ++i)
        af[i] = *(const i32x4*)(Ab + (wm + i * 16 + lm) * BK + ((gsel ^ sw) << 4));
#pragma unroll
      for (int j = 0; j < 4; ++j)
        bb[j] = *(const i32x4*)(Bb + (wn + j * 16 + lm) * BK + ((gsel ^ sw) << 4));
#pragma unroll
      for (int i = 0; i < 4; ++i)
#pragma unroll
        for (int j = 0; j < 4; ++j)
          acc[i][j] = __builtin_amdgcn_mfma_i32_16x16x64_i8(af[i], bb[j], acc[i][j], 0, 0, 0);
    }
  }
#undef STAGE

  float gamma = *gamma_p;
#pragma unroll
  for (int i = 0; i < 4; ++i) {
    int row0 = bm0 + wm + i * 16 + kg * 4;           // C/D: row = (lane>>4)*4 + reg
    f32x4 sv = *(const f32x4*)(srow + row0);         // 4 contiguous row steps, 16B aligned
#pragma unroll
    for (int j = 0; j < 4; ++j) {
      int col = bn0 + wn + j * 16 + lm;              // C/D: col = lane&15
      i32x4 v = acc[i][j];
#pragma unroll
      for (int r = 0; r < 4; ++r)
        C[(size_t)(row0 + r) * D_OUTER + col] = (float)v[r] * gamma * sv[r];
    }
  }
}

extern "C" void kernel_launch(void* const* d_in, const int* in_sizes, int n_in,
                              void* d_out, int out_size, void* d_ws, size_t ws_size,
                              hipStream_t stream) {
  const float* x = (const float*)d_in[0];   // [2,4096,2048]
  const float* w = (const float*)d_in[1];   // [2048,2048]
  const float* g = (const float*)d_in[2];   // [2048]
  float* out = (float*)d_out;               // [2,4096,2048] fp32

  float* gamma_p  = (float*)d_ws;                                  // 1 float
  float* partials = (float*)((char*)d_ws + 64);                    // 1024 floats
  float* srow     = (float*)((char*)d_ws + 8192);                  // 8192 floats (32 KB)
  i8* xn = (i8*)((char*)d_ws + 8192 + 32768);                      // 16 MB
  i8* wq = (i8*)((char*)d_ws + 8192 + 32768 + (size_t)MROWS * D_INNER);  // 4 MB

  prep_kernel<<<MROWS + NPART, 256, 0, stream>>>(x, g, w, xn, srow, partials);
  quant_kernel<<<2048, 256, 0, stream>>>(w, partials, gamma_p, wq);
  gemm_bt<<<dim3(D_OUTER / BN, MROWS / BM), 256, 0, stream>>>(xn, wq, gamma_p, srow, out);
}